// Round 7
// baseline (457.986 us; speedup 1.0000x reference)
//
#include <hip/hip_runtime.h>
#include <hip/hip_fp16.h>

// SDConv on MI355X.
// Reference: out = sum_k spmm(L_k, X) @ W_k + bias  (complex).
// Structure: apply W AFTER the spmm (k-expansion lives in the L domain), so the
// gather table is just X: 25.6 MB fp16 -> L2/L3-resident.
//   1. xh_kernel:  Xh[node][ch] = half2(Xr, Xi)                      (25.6 MB)
//   2. CSR build:  histogram -> scan -> payload scatter (16 B/edge: col + 6 L fp16).
//   3. row2_kernel: one wave per row; depth-2 software pipeline (payload + gather
//      prefetch in registers); 6 fp32 acc/lane; write Y[node][k][ch] fp16 (76.8 MB)
//   4. yw_kernel:  out = sum_k Y_k @ W_k + bias   (streaming VALU GEMM, fp32 acc)

constexpr int N_NODES = 100000;
constexpr int E_EDGES = 1600000;
constexpr int CH = 64;
constexpr int NP = 100096;          // N padded to multiple of 256
constexpr int NBLK = NP / 256;      // 391

typedef float f32x4 __attribute__((ext_vector_type(4)));
typedef unsigned u32x4 __attribute__((ext_vector_type(4)));

__global__ __launch_bounds__(256) void init_out_kernel(const float* __restrict__ bias,
                                                       float* __restrict__ out) {
    int i = blockIdx.x * 256 + threadIdx.x;
    out[i] = bias[i & 63];
}

// ---------------- Phase 1: Xh = half2(Xr, Xi), [N][64] ----------------
__global__ __launch_bounds__(256) void xh_kernel(const float* __restrict__ Xr,
                                                 const float* __restrict__ Xi,
                                                 __half2* __restrict__ Xh) {
    int i = blockIdx.x * 256 + threadIdx.x;   // grid = N*64/4/256 = 6250 exact
    const float4 r = ((const float4*)Xr)[i];
    const float4 m = ((const float4*)Xi)[i];
    __half2 h0 = __floats2half2_rn(r.x, m.x);
    __half2 h1 = __floats2half2_rn(r.y, m.y);
    __half2 h2 = __floats2half2_rn(r.z, m.z);
    __half2 h3 = __floats2half2_rn(r.w, m.w);
    uint4 u;
    u.x = __builtin_bit_cast(unsigned, h0);
    u.y = __builtin_bit_cast(unsigned, h1);
    u.z = __builtin_bit_cast(unsigned, h2);
    u.w = __builtin_bit_cast(unsigned, h3);
    ((uint4*)Xh)[i] = u;
}

// ---------------- CSR build ----------------
__global__ __launch_bounds__(256) void zero_counts_kernel(int* __restrict__ counts) {
    counts[blockIdx.x * 256 + threadIdx.x] = 0;   // grid = NBLK
}

__global__ __launch_bounds__(256) void hist_kernel(const int* __restrict__ rows,
                                                   int* __restrict__ counts) {
    int e = blockIdx.x * 256 + threadIdx.x;
    if (e < E_EDGES) atomicAdd(&counts[rows[e]], 1);
}

__global__ __launch_bounds__(256) void scan_a_kernel(const int* __restrict__ counts,
                                                     int* __restrict__ rowst,
                                                     int* __restrict__ btot) {
    __shared__ int s[256];
    const int t = threadIdx.x;
    const int g = blockIdx.x * 256 + t;
    int v = counts[g];
    s[t] = v;
    __syncthreads();
    for (int off = 1; off < 256; off <<= 1) {
        int a = (t >= off) ? s[t - off] : 0;
        __syncthreads();
        s[t] += a;
        __syncthreads();
    }
    rowst[g] = s[t] - v;
    if (t == 255) btot[blockIdx.x] = s[255];
}

__global__ __launch_bounds__(512) void scan_b_kernel(int* __restrict__ btot) {
    __shared__ int s[512];
    const int t = threadIdx.x;
    int v = (t < NBLK) ? btot[t] : 0;
    s[t] = v;
    __syncthreads();
    for (int off = 1; off < 512; off <<= 1) {
        int a = (t >= off) ? s[t - off] : 0;
        __syncthreads();
        s[t] += a;
        __syncthreads();
    }
    if (t < NBLK) btot[t] = s[t] - v;
}

__global__ __launch_bounds__(256) void scan_c_kernel(const int* __restrict__ btot,
                                                     int* __restrict__ rowst,
                                                     int* __restrict__ cursor) {
    const int g = blockIdx.x * 256 + threadIdx.x;
    int v = rowst[g] + btot[blockIdx.x];
    rowst[g] = v;
    cursor[g] = v;
}

// payload per edge: uint4 = {col, half2(lr0,li0), half2(lr1,li1), half2(lr2,li2)}
__global__ __launch_bounds__(256) void scatter_kernel(const int* __restrict__ rows,
                                                      const int* __restrict__ cols,
                                                      const float* __restrict__ Lr,
                                                      const float* __restrict__ Li,
                                                      int* __restrict__ cursor,
                                                      uint4* __restrict__ payload) {
    int e = blockIdx.x * 256 + threadIdx.x;
    if (e >= E_EDGES) return;
    int r = rows[e];
    int pos = atomicAdd(&cursor[r], 1);
    uint4 u;
    u.x = (unsigned)cols[e];
    u.y = __builtin_bit_cast(unsigned, __floats2half2_rn(Lr[e], Li[e]));
    u.z = __builtin_bit_cast(unsigned, __floats2half2_rn(Lr[E_EDGES + e], Li[E_EDGES + e]));
    u.w = __builtin_bit_cast(unsigned,
                             __floats2half2_rn(Lr[2 * E_EDGES + e], Li[2 * E_EDGES + e]));
    payload[pos] = u;
}

// ---------------- Main pass: one wave per row, depth-2 pipelined ----------------
__global__ __launch_bounds__(256) void row2_kernel(const int* __restrict__ rowst,
                                                   const unsigned* __restrict__ payload,
                                                   const __half2* __restrict__ Xh,
                                                   __half2* __restrict__ Y) {
    const int r = blockIdx.x * 4 + (threadIdx.x >> 6);
    const int lane = threadIdx.x & 63;
    if (r >= N_NODES) return;
    const int start = rowst[r];
    const int end = rowst[r + 1];
    float aR0 = 0.f, aI0 = 0.f, aR1 = 0.f, aI1 = 0.f, aR2 = 0.f, aI2 = 0.f;

    auto accum = [&](const u32x4& pay, const float2& xv) {
        float2 l0 = __half22float2(__builtin_bit_cast(__half2, (unsigned)pay.y));
        float2 l1 = __half22float2(__builtin_bit_cast(__half2, (unsigned)pay.z));
        float2 l2 = __half22float2(__builtin_bit_cast(__half2, (unsigned)pay.w));
        aR0 += l0.x * xv.x - l0.y * xv.y;
        aI0 += l0.y * xv.x + l0.x * xv.y;
        aR1 += l1.x * xv.x - l1.y * xv.y;
        aI1 += l1.y * xv.x + l1.x * xv.y;
        aR2 += l2.x * xv.x - l2.y * xv.y;
        aI2 += l2.y * xv.x + l2.x * xv.y;
    };

    int p = start;
    if (p < end) {
        const u32x4* pp = (const u32x4*)payload;
        u32x4 payA = __builtin_nontemporal_load(pp + p);
        u32x4 payB = payA;
        if (p + 1 < end) payB = __builtin_nontemporal_load(pp + p + 1);
        float2 xA = __half22float2(Xh[(size_t)payA.x * 64 + lane]);
        for (; p + 2 < end; ++p) {
            u32x4 payC = __builtin_nontemporal_load(pp + p + 2);
            float2 xB = __half22float2(Xh[(size_t)payB.x * 64 + lane]);
            accum(payA, xA);
            payA = payB;
            xA = xB;
            payB = payC;
        }
        if (p + 1 < end) {
            float2 xB = __half22float2(Xh[(size_t)payB.x * 64 + lane]);
            accum(payA, xA);
            payA = payB;
            xA = xB;
        }
        accum(payA, xA);
    }

    __half2* yp = Y + (size_t)r * 192;
    __builtin_nontemporal_store(
        __builtin_bit_cast(unsigned, __floats2half2_rn(aR0, aI0)), (unsigned*)(yp + lane));
    __builtin_nontemporal_store(
        __builtin_bit_cast(unsigned, __floats2half2_rn(aR1, aI1)), (unsigned*)(yp + 64 + lane));
    __builtin_nontemporal_store(
        __builtin_bit_cast(unsigned, __floats2half2_rn(aR2, aI2)), (unsigned*)(yp + 128 + lane));
}

// ---------------- Phase 4: out = sum_k Y_k @ W_k + bias ----------------
// Y: [N][3][64] half2(re,im). W: [3][64][64] fp32. 32-row tiles, 8 rows/wave.
__global__ __launch_bounds__(256) void yw_kernel(const __half2* __restrict__ Y,
                                                 const float* __restrict__ W,
                                                 const float* __restrict__ bias,
                                                 float* __restrict__ out) {
    __shared__ float sW[3][64][64];      // 48 KB
    __shared__ __half2 sY[32][3][64];    // 24 KB
    const int tid = threadIdx.x;

    float4* swf = (float4*)&sW[0][0][0];
    const float4* gW = (const float4*)W;
    for (int i = tid; i < 3 * 1024; i += 256) swf[i] = gW[i];

    const int rowbase = blockIdx.x * 32;                 // grid = N/32 = 3125 exact
    float4* syf = (float4*)&sY[0][0][0];
    const float4* gY = (const float4*)(Y + (size_t)rowbase * 192);
    for (int i = tid; i < 1536; i += 256) syf[i] = gY[i];
    __syncthreads();

    const int col = tid & 63;
    const int rg = tid >> 6;
    const float b = bias[col];

    float accR[8], accI[8];
#pragma unroll
    for (int i = 0; i < 8; ++i) { accR[i] = 0.f; accI[i] = 0.f; }

#pragma unroll
    for (int k = 0; k < 3; ++k) {
#pragma unroll
        for (int j8 = 0; j8 < 8; ++j8) {
            float w[8];
#pragma unroll
            for (int jj = 0; jj < 8; ++jj) w[jj] = sW[k][j8 * 8 + jj][col];  // conflict-free
#pragma unroll
            for (int i = 0; i < 8; ++i) {
                const f32x4* yv = (const f32x4*)&sY[rg * 8 + i][k][j8 * 8];
#pragma unroll
                for (int h = 0; h < 2; ++h) {
                    f32x4 y4 = yv[h];
                    float ys[4] = {y4.x, y4.y, y4.z, y4.w};
#pragma unroll
                    for (int q = 0; q < 4; ++q) {
                        float2 v = __half22float2(__builtin_bit_cast(__half2, ys[q]));
                        accR[i] += v.x * w[h * 4 + q];
                        accI[i] += v.y * w[h * 4 + q];
                    }
                }
            }
        }
    }

#pragma unroll
    for (int i = 0; i < 8; ++i) {
        const int row = rowbase + rg * 8 + i;
        __builtin_nontemporal_store(accR[i] + b, &out[(size_t)row * 64 + col]);
        __builtin_nontemporal_store(accI[i] + b, &out[(size_t)(N_NODES + row) * 64 + col]);
    }
}

// ================= Fallback kernels (small-ws paths) =================
template <int NK>
__global__ __launch_bounds__(256) void xw_kernel(const float* __restrict__ Xr,
                                                 const float* __restrict__ Xi,
                                                 const float* __restrict__ W,
                                                 __half2* __restrict__ XWh) {
    __shared__ float sW[NK][64][64];
    __shared__ float4 sX4[2][32][16];
    const int tid = threadIdx.x;

    float4* swf = (float4*)&sW[0][0][0];
    const float4* gW = (const float4*)W;
    for (int i = tid; i < NK * 1024; i += 256) swf[i] = gW[i];

    const int rowbase = blockIdx.x * 32;
    float4* sxf = (float4*)sX4;
    const float4* gXr = (const float4*)(Xr + (size_t)rowbase * CH);
    const float4* gXi = (const float4*)(Xi + (size_t)rowbase * CH);
    for (int i = tid; i < 512; i += 256) {
        sxf[i] = gXr[i];
        sxf[512 + i] = gXi[i];
    }
    __syncthreads();

    const int col = tid & 63;
    const int rg = tid >> 6;

    float acc[8][2 * NK];
#pragma unroll
    for (int i = 0; i < 8; ++i)
#pragma unroll
        for (int c2 = 0; c2 < 2 * NK; ++c2) acc[i][c2] = 0.0f;

#pragma unroll 2
    for (int j4 = 0; j4 < 16; ++j4) {
        float w[NK][4];
#pragma unroll
        for (int k = 0; k < NK; ++k)
#pragma unroll
            for (int jj = 0; jj < 4; ++jj) w[k][jj] = sW[k][j4 * 4 + jj][col];
#pragma unroll
        for (int i = 0; i < 8; ++i) {
            float4 xr = sX4[0][rg * 8 + i][j4];
            float4 xi = sX4[1][rg * 8 + i][j4];
            const float xra[4] = {xr.x, xr.y, xr.z, xr.w};
            const float xia[4] = {xi.x, xi.y, xi.z, xi.w};
#pragma unroll
            for (int jj = 0; jj < 4; ++jj)
#pragma unroll
                for (int k = 0; k < NK; ++k) {
                    acc[i][2 * k] += xra[jj] * w[k][jj];
                    acc[i][2 * k + 1] += xia[jj] * w[k][jj];
                }
        }
    }

#pragma unroll
    for (int i = 0; i < 8; ++i) {
        __half2* dst = XWh + (size_t)(rowbase + rg * 8 + i) * (NK * 64);
#pragma unroll
        for (int k = 0; k < NK; ++k)
            dst[k * 64 + col] = __floats2half2_rn(acc[i][2 * k], acc[i][2 * k + 1]);
    }
}

template <int NK>
__global__ __launch_bounds__(256) void edge_kernel(const int* __restrict__ rows,
                                                   const int* __restrict__ cols,
                                                   const float* __restrict__ Lr,
                                                   const float* __restrict__ Li,
                                                   const __half2* __restrict__ XWh,
                                                   float* __restrict__ out) {
    const int gid = blockIdx.x * 256 + threadIdx.x;
    const int e = gid >> 6;
    const int lane = gid & 63;
    if (e >= E_EDGES) return;

    const int row = rows[e];
    const int colN = cols[e];
    const __half2* xw = XWh + (size_t)colN * (NK * 64);

    float rc = 0.0f, ic = 0.0f;
#pragma unroll
    for (int k = 0; k < NK; ++k) {
        const float lr = Lr[(size_t)k * E_EDGES + e];
        const float li = Li[(size_t)k * E_EDGES + e];
        float2 v = __half22float2(xw[k * 64 + lane]);
        rc += lr * v.x - li * v.y;
        ic += li * v.x + lr * v.y;
    }
    unsafeAtomicAdd(out + (size_t)row * 64 + lane, rc);
    unsafeAtomicAdd(out + ((size_t)N_NODES + row) * 64 + lane, ic);
}

extern "C" void kernel_launch(void* const* d_in, const int* in_sizes, int n_in,
                              void* d_out, int out_size, void* d_ws, size_t ws_size,
                              hipStream_t stream) {
    const float* Xr = (const float*)d_in[0];
    const float* Xi = (const float*)d_in[1];
    const int* ei = (const int*)d_in[2];
    const float* Lr = (const float*)d_in[3];
    const float* Li = (const float*)d_in[4];
    const float* W = (const float*)d_in[5];
    const float* bias = (const float*)d_in[6];
    float* out = (float*)d_out;

    const int* rows = ei;
    const int* cols = ei + E_EDGES;

    char* wsb = (char*)d_ws;
    const int e_grid = E_EDGES / 256;                             // 6250
    const int edge_grid = (int)((size_t)E_EDGES * 64 / 256);      // 400000
    const int gemm_grid = N_NODES / 32;                           // 3125

    // Main-path ws layout
    __half2* Xh = (__half2*)wsb;                                  //  25,600,000 B
    __half2* Y = (__half2*)(wsb + 25600000);                      //  76,800,000 B
    unsigned* payload = (unsigned*)(wsb + 102400000);             //  25,600,000 B (16 B/edge)
    int* counts = (int*)(wsb + 128000000);                        //     400,384 B
    int* rowst = (int*)(wsb + 128400384);                         //     400,384 B
    int* cursor = (int*)(wsb + 128800768);                        //     400,384 B
    int* btot = (int*)(wsb + 129201152);                          //       2,048 B
    const size_t need_new = 129203200;

    if (ws_size >= need_new) {
        xh_kernel<<<6250, 256, 0, stream>>>(Xr, Xi, Xh);
        zero_counts_kernel<<<NBLK, 256, 0, stream>>>(counts);
        hist_kernel<<<e_grid, 256, 0, stream>>>(rows, counts);
        scan_a_kernel<<<NBLK, 256, 0, stream>>>(counts, rowst, btot);
        scan_b_kernel<<<1, 512, 0, stream>>>(btot);
        scan_c_kernel<<<NBLK, 256, 0, stream>>>(btot, rowst, cursor);
        scatter_kernel<<<e_grid, 256, 0, stream>>>(rows, cols, Lr, Li, cursor,
                                                   (uint4*)payload);
        row2_kernel<<<(N_NODES + 3) / 4, 256, 0, stream>>>(rowst, payload, Xh, Y);
        yw_kernel<<<gemm_grid, 256, 0, stream>>>(Y, W, bias, out);
        return;
    }

    // Fallback ws layout (atomic edge scatter over XWh table)
    __half2* XWh = (__half2*)wsb;                                 //  76,800,000 B
    const size_t need_onepass = 76800000;

    if (ws_size >= need_onepass) {
        init_out_kernel<<<2 * N_NODES * CH / 256, 256, 0, stream>>>(bias, out);
        xw_kernel<3><<<gemm_grid, 256, 0, stream>>>(Xr, Xi, W, XWh);
        edge_kernel<3><<<edge_grid, 256, 0, stream>>>(rows, cols, Lr, Li, XWh, out);
    } else {
        init_out_kernel<<<2 * N_NODES * CH / 256, 256, 0, stream>>>(bias, out);
        for (int k = 0; k < 3; ++k) {
            xw_kernel<1><<<gemm_grid, 256, 0, stream>>>(Xr, Xi, W + (size_t)k * 4096, XWh);
            edge_kernel<1><<<edge_grid, 256, 0, stream>>>(rows, cols,
                                                          Lr + (size_t)k * E_EDGES,
                                                          Li + (size_t)k * E_EDGES, XWh, out);
        }
    }
}

// Round 8
// 396.534 us; speedup vs baseline: 1.1550x; 1.1550x over previous
//
#include <hip/hip_runtime.h>
#include <hip/hip_fp16.h>

// SDConv on MI355X.
// Reference: out = sum_k spmm(L_k, X) @ W_k + bias  (complex).
// Structure: apply W AFTER the spmm (k-expansion lives in the L domain), so the
// gather table is just X: 25.6 MB fp16 -> L2/L3-resident.
//   1. xh_zero_kernel: Xh[node][ch] = half2(Xr, Xi); also zeros hist counters.
//   2. CSR build:  histogram -> scan -> payload scatter (16 B/edge: col + 6 L fp16).
//   3. row2_kernel: one wave per row; complex MAC as 2x v_dot2_f32_f16 per k
//      (no f16->f32 converts); writes Y planar f16: Yre[n][192], Yim[n][192].
//   4. yw2_kernel:  out = sum_k Y_k @ W_k + bias as packed-pair dot2 GEMM, f32 acc.

constexpr int N_NODES = 100000;
constexpr int E_EDGES = 1600000;
constexpr int CH = 64;
constexpr int NP = 100096;          // N padded to multiple of 256
constexpr int NBLK = NP / 256;      // 391

typedef float f32x4 __attribute__((ext_vector_type(4)));
typedef unsigned u32x4 __attribute__((ext_vector_type(4)));
typedef unsigned u32x2 __attribute__((ext_vector_type(2)));
typedef _Float16 h2f __attribute__((ext_vector_type(2)));

// f32 += dot(half2, half2) with f32 accumulation (v_dot2_f32_f16).
__device__ __forceinline__ float fdot2h(unsigned a, unsigned b, float c) {
#if __has_builtin(__builtin_amdgcn_fdot2)
    return __builtin_amdgcn_fdot2(__builtin_bit_cast(h2f, a),
                                  __builtin_bit_cast(h2f, b), c, false);
#else
    float2 af = __half22float2(__builtin_bit_cast(__half2, a));
    float2 bf = __half22float2(__builtin_bit_cast(__half2, b));
    return c + af.x * bf.x + af.y * bf.y;
#endif
}

__global__ __launch_bounds__(256) void init_out_kernel(const float* __restrict__ bias,
                                                       float* __restrict__ out) {
    int i = blockIdx.x * 256 + threadIdx.x;
    out[i] = bias[i & 63];
}

// ---------------- Phase 1: Xh = half2(Xr, Xi), [N][64]; zero hist counts ----------------
__global__ __launch_bounds__(256) void xh_zero_kernel(const float* __restrict__ Xr,
                                                      const float* __restrict__ Xi,
                                                      unsigned* __restrict__ Xh,
                                                      int* __restrict__ counts) {
    int i = blockIdx.x * 256 + threadIdx.x;   // grid = N*64/4/256 = 6250 exact
    if (i < NP) counts[i] = 0;
    const float4 r = ((const float4*)Xr)[i];
    const float4 m = ((const float4*)Xi)[i];
    uint4 u;
    u.x = __builtin_bit_cast(unsigned, __floats2half2_rn(r.x, m.x));
    u.y = __builtin_bit_cast(unsigned, __floats2half2_rn(r.y, m.y));
    u.z = __builtin_bit_cast(unsigned, __floats2half2_rn(r.z, m.z));
    u.w = __builtin_bit_cast(unsigned, __floats2half2_rn(r.w, m.w));
    ((uint4*)Xh)[i] = u;
}

// ---------------- CSR build ----------------
__global__ __launch_bounds__(256) void hist_kernel(const int* __restrict__ rows,
                                                   int* __restrict__ counts) {
    int e = blockIdx.x * 256 + threadIdx.x;
    if (e < E_EDGES) atomicAdd(&counts[rows[e]], 1);
}

__global__ __launch_bounds__(256) void scan_a_kernel(const int* __restrict__ counts,
                                                     int* __restrict__ rowst,
                                                     int* __restrict__ btot) {
    __shared__ int s[256];
    const int t = threadIdx.x;
    const int g = blockIdx.x * 256 + t;
    int v = counts[g];
    s[t] = v;
    __syncthreads();
    for (int off = 1; off < 256; off <<= 1) {
        int a = (t >= off) ? s[t - off] : 0;
        __syncthreads();
        s[t] += a;
        __syncthreads();
    }
    rowst[g] = s[t] - v;
    if (t == 255) btot[blockIdx.x] = s[255];
}

__global__ __launch_bounds__(512) void scan_b_kernel(int* __restrict__ btot) {
    __shared__ int s[512];
    const int t = threadIdx.x;
    int v = (t < NBLK) ? btot[t] : 0;
    s[t] = v;
    __syncthreads();
    for (int off = 1; off < 512; off <<= 1) {
        int a = (t >= off) ? s[t - off] : 0;
        __syncthreads();
        s[t] += a;
        __syncthreads();
    }
    if (t < NBLK) btot[t] = s[t] - v;
}

__global__ __launch_bounds__(256) void scan_c_kernel(const int* __restrict__ btot,
                                                     int* __restrict__ rowst,
                                                     int* __restrict__ cursor) {
    const int g = blockIdx.x * 256 + threadIdx.x;
    int v = rowst[g] + btot[blockIdx.x];
    rowst[g] = v;
    cursor[g] = v;
}

// payload per edge: uint4 = {col, half2(lr0,li0), half2(lr1,li1), half2(lr2,li2)}
__global__ __launch_bounds__(256) void scatter_kernel(const int* __restrict__ rows,
                                                      const int* __restrict__ cols,
                                                      const float* __restrict__ Lr,
                                                      const float* __restrict__ Li,
                                                      int* __restrict__ cursor,
                                                      uint4* __restrict__ payload) {
    int e = blockIdx.x * 256 + threadIdx.x;
    if (e >= E_EDGES) return;
    int r = rows[e];
    int pos = atomicAdd(&cursor[r], 1);
    uint4 u;
    u.x = (unsigned)cols[e];
    u.y = __builtin_bit_cast(unsigned, __floats2half2_rn(Lr[e], Li[e]));
    u.z = __builtin_bit_cast(unsigned, __floats2half2_rn(Lr[E_EDGES + e], Li[E_EDGES + e]));
    u.w = __builtin_bit_cast(unsigned,
                             __floats2half2_rn(Lr[2 * E_EDGES + e], Li[2 * E_EDGES + e]));
    payload[pos] = u;
}

// ---------------- Main pass: one wave per row, dot2 complex MAC ----------------
__global__ __launch_bounds__(256) void row2_kernel(const int* __restrict__ rowst,
                                                   const unsigned* __restrict__ payload,
                                                   const unsigned* __restrict__ Xh,
                                                   __half* __restrict__ Yre,
                                                   __half* __restrict__ Yim) {
    const int r = blockIdx.x * 4 + (threadIdx.x >> 6);
    const int lane = threadIdx.x & 63;
    if (r >= N_NODES) return;
    const int start = rowst[r];
    const int end = rowst[r + 1];
    float aR0 = 0.f, aI0 = 0.f, aR1 = 0.f, aI1 = 0.f, aR2 = 0.f, aI2 = 0.f;

    auto accum = [&](const u32x4& pay, unsigned xv) {
        const unsigned u0 = pay.y, u1 = pay.z, u2 = pay.w;
        // aR += lr*xr - li*xi = dot2((lr,-li),(xr,xi)); aI += li*xr + lr*xi = dot2((li,lr),(xr,xi))
        aR0 = fdot2h(u0 ^ 0x80000000u, xv, aR0);
        aI0 = fdot2h((u0 >> 16) | (u0 << 16), xv, aI0);
        aR1 = fdot2h(u1 ^ 0x80000000u, xv, aR1);
        aI1 = fdot2h((u1 >> 16) | (u1 << 16), xv, aI1);
        aR2 = fdot2h(u2 ^ 0x80000000u, xv, aR2);
        aI2 = fdot2h((u2 >> 16) | (u2 << 16), xv, aI2);
    };

    int p = start;
    if (p < end) {
        const u32x4* pp = (const u32x4*)payload;
        u32x4 payA = __builtin_nontemporal_load(pp + p);
        u32x4 payB = payA;
        if (p + 1 < end) payB = __builtin_nontemporal_load(pp + p + 1);
        unsigned xA = Xh[(size_t)payA.x * 64 + lane];
        for (; p + 2 < end; ++p) {
            u32x4 payC = __builtin_nontemporal_load(pp + p + 2);
            unsigned xB = Xh[(size_t)payB.x * 64 + lane];
            accum(payA, xA);
            payA = payB;
            xA = xB;
            payB = payC;
        }
        if (p + 1 < end) {
            unsigned xB = Xh[(size_t)payB.x * 64 + lane];
            accum(payA, xA);
            payA = payB;
            xA = xB;
        }
        accum(payA, xA);
    }

    __half* yr = Yre + (size_t)r * 192;
    __half* yi = Yim + (size_t)r * 192;
    yr[lane] = __float2half(aR0);
    yr[64 + lane] = __float2half(aR1);
    yr[128 + lane] = __float2half(aR2);
    yi[lane] = __float2half(aI0);
    yi[64 + lane] = __float2half(aI1);
    yi[128 + lane] = __float2half(aI2);
}

// ---------------- Phase 4: out = Y @ Wcat + bias via packed-pair dot2 ----------------
// Yre/Yim: [N][192] f16 (t = k*64 + j). Wcat: [192][64] f32 (row-major [3][64][64]).
__global__ __launch_bounds__(256) void yw2_kernel(const __half* __restrict__ Yre,
                                                  const __half* __restrict__ Yim,
                                                  const float* __restrict__ W,
                                                  const float* __restrict__ bias,
                                                  float* __restrict__ out) {
    __shared__ unsigned sW2[96][64];     // [t-pair][col] = half2(W[2t][c], W[2t+1][c])  24 KB
    __shared__ unsigned sY[2][32][96];   // [re/im][row][t-pair]                          24 KB
    const int tid = threadIdx.x;

    for (int idx = tid; idx < 96 * 64; idx += 256) {
        const int kp = idx >> 6, c = idx & 63;
        sW2[kp][c] = __builtin_bit_cast(
            unsigned, __floats2half2_rn(W[(2 * kp) * 64 + c], W[(2 * kp + 1) * 64 + c]));
    }

    const int rowbase = blockIdx.x * 32;                 // grid = N/32 = 3125 exact
    const uint4* gYr = (const uint4*)(Yre + (size_t)rowbase * 192);
    const uint4* gYi = (const uint4*)(Yim + (size_t)rowbase * 192);
    uint4* sYr4 = (uint4*)&sY[0][0][0];
    uint4* sYi4 = (uint4*)&sY[1][0][0];
    for (int i = tid; i < 768; i += 256) {
        sYr4[i] = gYr[i];
        sYi4[i] = gYi[i];
    }
    __syncthreads();

    const int col = tid & 63;
    const int rg = tid >> 6;
    const float b = bias[col];

    float accR[8], accI[8];
#pragma unroll
    for (int i = 0; i < 8; ++i) { accR[i] = 0.f; accI[i] = 0.f; }

#pragma unroll 4
    for (int kpp = 0; kpp < 48; ++kpp) {
        const unsigned w0 = sW2[2 * kpp][col];       // stride-1 across lanes: conflict-free
        const unsigned w1 = sW2[2 * kpp + 1][col];
#pragma unroll
        for (int i = 0; i < 8; ++i) {
            const int row = rg * 8 + i;
            u32x2 yr = *(const u32x2*)&sY[0][row][2 * kpp];   // uniform addr -> broadcast
            u32x2 yi = *(const u32x2*)&sY[1][row][2 * kpp];
            accR[i] = fdot2h(yr.x, w0, accR[i]);
            accR[i] = fdot2h(yr.y, w1, accR[i]);
            accI[i] = fdot2h(yi.x, w0, accI[i]);
            accI[i] = fdot2h(yi.y, w1, accI[i]);
        }
    }

#pragma unroll
    for (int i = 0; i < 8; ++i) {
        const int row = rowbase + rg * 8 + i;
        __builtin_nontemporal_store(accR[i] + b, &out[(size_t)row * 64 + col]);
        __builtin_nontemporal_store(accI[i] + b, &out[(size_t)(N_NODES + row) * 64 + col]);
    }
}

// ================= Fallback kernels (small-ws paths) =================
template <int NK>
__global__ __launch_bounds__(256) void xw_kernel(const float* __restrict__ Xr,
                                                 const float* __restrict__ Xi,
                                                 const float* __restrict__ W,
                                                 __half2* __restrict__ XWh) {
    __shared__ float sW[NK][64][64];
    __shared__ float4 sX4[2][32][16];
    const int tid = threadIdx.x;

    float4* swf = (float4*)&sW[0][0][0];
    const float4* gW = (const float4*)W;
    for (int i = tid; i < NK * 1024; i += 256) swf[i] = gW[i];

    const int rowbase = blockIdx.x * 32;
    float4* sxf = (float4*)sX4;
    const float4* gXr = (const float4*)(Xr + (size_t)rowbase * CH);
    const float4* gXi = (const float4*)(Xi + (size_t)rowbase * CH);
    for (int i = tid; i < 512; i += 256) {
        sxf[i] = gXr[i];
        sxf[512 + i] = gXi[i];
    }
    __syncthreads();

    const int col = tid & 63;
    const int rg = tid >> 6;

    float acc[8][2 * NK];
#pragma unroll
    for (int i = 0; i < 8; ++i)
#pragma unroll
        for (int c2 = 0; c2 < 2 * NK; ++c2) acc[i][c2] = 0.0f;

#pragma unroll 2
    for (int j4 = 0; j4 < 16; ++j4) {
        float w[NK][4];
#pragma unroll
        for (int k = 0; k < NK; ++k)
#pragma unroll
            for (int jj = 0; jj < 4; ++jj) w[k][jj] = sW[k][j4 * 4 + jj][col];
#pragma unroll
        for (int i = 0; i < 8; ++i) {
            float4 xr = sX4[0][rg * 8 + i][j4];
            float4 xi = sX4[1][rg * 8 + i][j4];
            const float xra[4] = {xr.x, xr.y, xr.z, xr.w};
            const float xia[4] = {xi.x, xi.y, xi.z, xi.w};
#pragma unroll
            for (int jj = 0; jj < 4; ++jj)
#pragma unroll
                for (int k = 0; k < NK; ++k) {
                    acc[i][2 * k] += xra[jj] * w[k][jj];
                    acc[i][2 * k + 1] += xia[jj] * w[k][jj];
                }
        }
    }

#pragma unroll
    for (int i = 0; i < 8; ++i) {
        __half2* dst = XWh + (size_t)(rowbase + rg * 8 + i) * (NK * 64);
#pragma unroll
        for (int k = 0; k < NK; ++k)
            dst[k * 64 + col] = __floats2half2_rn(acc[i][2 * k], acc[i][2 * k + 1]);
    }
}

template <int NK>
__global__ __launch_bounds__(256) void edge_kernel(const int* __restrict__ rows,
                                                   const int* __restrict__ cols,
                                                   const float* __restrict__ Lr,
                                                   const float* __restrict__ Li,
                                                   const __half2* __restrict__ XWh,
                                                   float* __restrict__ out) {
    const int gid = blockIdx.x * 256 + threadIdx.x;
    const int e = gid >> 6;
    const int lane = gid & 63;
    if (e >= E_EDGES) return;

    const int row = rows[e];
    const int colN = cols[e];
    const __half2* xw = XWh + (size_t)colN * (NK * 64);

    float rc = 0.0f, ic = 0.0f;
#pragma unroll
    for (int k = 0; k < NK; ++k) {
        const float lr = Lr[(size_t)k * E_EDGES + e];
        const float li = Li[(size_t)k * E_EDGES + e];
        float2 v = __half22float2(xw[k * 64 + lane]);
        rc += lr * v.x - li * v.y;
        ic += li * v.x + lr * v.y;
    }
    unsafeAtomicAdd(out + (size_t)row * 64 + lane, rc);
    unsafeAtomicAdd(out + ((size_t)N_NODES + row) * 64 + lane, ic);
}

extern "C" void kernel_launch(void* const* d_in, const int* in_sizes, int n_in,
                              void* d_out, int out_size, void* d_ws, size_t ws_size,
                              hipStream_t stream) {
    const float* Xr = (const float*)d_in[0];
    const float* Xi = (const float*)d_in[1];
    const int* ei = (const int*)d_in[2];
    const float* Lr = (const float*)d_in[3];
    const float* Li = (const float*)d_in[4];
    const float* W = (const float*)d_in[5];
    const float* bias = (const float*)d_in[6];
    float* out = (float*)d_out;

    const int* rows = ei;
    const int* cols = ei + E_EDGES;

    char* wsb = (char*)d_ws;
    const int e_grid = E_EDGES / 256;                             // 6250
    const int edge_grid = (int)((size_t)E_EDGES * 64 / 256);      // 400000
    const int gemm_grid = N_NODES / 32;                           // 3125

    // Main-path ws layout
    unsigned* Xh = (unsigned*)wsb;                                //  25,600,000 B
    __half* Yre = (__half*)(wsb + 25600000);                      //  38,400,000 B
    __half* Yim = (__half*)(wsb + 64000000);                      //  38,400,000 B
    unsigned* payload = (unsigned*)(wsb + 102400000);             //  25,600,000 B (16 B/edge)
    int* counts = (int*)(wsb + 128000000);                        //     400,384 B
    int* rowst = (int*)(wsb + 128400384);                         //     400,384 B
    int* cursor = (int*)(wsb + 128800768);                        //     400,384 B
    int* btot = (int*)(wsb + 129201152);                          //       2,048 B
    const size_t need_new = 129203200;

    if (ws_size >= need_new) {
        xh_zero_kernel<<<6250, 256, 0, stream>>>(Xr, Xi, Xh, counts);
        hist_kernel<<<e_grid, 256, 0, stream>>>(rows, counts);
        scan_a_kernel<<<NBLK, 256, 0, stream>>>(counts, rowst, btot);
        scan_b_kernel<<<1, 512, 0, stream>>>(btot);
        scan_c_kernel<<<NBLK, 256, 0, stream>>>(btot, rowst, cursor);
        scatter_kernel<<<e_grid, 256, 0, stream>>>(rows, cols, Lr, Li, cursor,
                                                   (uint4*)payload);
        row2_kernel<<<(N_NODES + 3) / 4, 256, 0, stream>>>(rowst, payload, Xh, Yre, Yim);
        yw2_kernel<<<gemm_grid, 256, 0, stream>>>(Yre, Yim, W, bias, out);
        return;
    }

    // Fallback ws layout (atomic edge scatter over XWh table)
    __half2* XWh = (__half2*)wsb;                                 //  76,800,000 B
    const size_t need_onepass = 76800000;

    if (ws_size >= need_onepass) {
        init_out_kernel<<<2 * N_NODES * CH / 256, 256, 0, stream>>>(bias, out);
        xw_kernel<3><<<gemm_grid, 256, 0, stream>>>(Xr, Xi, W, XWh);
        edge_kernel<3><<<edge_grid, 256, 0, stream>>>(rows, cols, Lr, Li, XWh, out);
    } else {
        init_out_kernel<<<2 * N_NODES * CH / 256, 256, 0, stream>>>(bias, out);
        for (int k = 0; k < 3; ++k) {
            xw_kernel<1><<<gemm_grid, 256, 0, stream>>>(Xr, Xi, W + (size_t)k * 4096, XWh);
            edge_kernel<1><<<edge_grid, 256, 0, stream>>>(rows, cols,
                                                          Lr + (size_t)k * E_EDGES,
                                                          Li + (size_t)k * E_EDGES, XWh, out);
        }
    }
}

// Round 9
// 337.419 us; speedup vs baseline: 1.3573x; 1.1752x over previous
//
#include <hip/hip_runtime.h>
#include <hip/hip_fp16.h>

// SDConv on MI355X.
// Reference: out = sum_k spmm(L_k, X) @ W_k + bias  (complex).
// Structure: apply W AFTER the spmm (k-expansion lives in the L domain), so the
// gather table is just X: 25.6 MB fp16 -> L2/L3-resident.
//   1. xh_zero_kernel: Xh[node][ch] = half2(Xr, Xi); also zeros hist counters.
//   2. CSR build: histogram -> scan -> payload scatter (32 B/edge, PRE-SWIZZLED
//      L pairs: {col, (lr,-li)k, (li,lr)k}) so row pass needs zero bit-ops.
//   3. row3_kernel: one wave per row; wave-uniform row (readfirstlane) so payload
//      reads go through the SCALAR pipe (s_load_dwordx8); depth-3 payload /
//      depth-2 gather software pipeline; accum = 6x v_dot2_f32_f16 per edge.
//      Writes Y planar f16: Yre[n][192], Yim[n][192].
//   4. yw2_kernel:  out = sum_k Y_k @ W_k + bias as packed-pair dot2 GEMM, f32 acc.

constexpr int N_NODES = 100000;
constexpr int E_EDGES = 1600000;
constexpr int CH = 64;
constexpr int NP = 100096;          // N padded to multiple of 256
constexpr int NBLK = NP / 256;      // 391

typedef float f32x4 __attribute__((ext_vector_type(4)));
typedef unsigned u32x2 __attribute__((ext_vector_type(2)));
typedef _Float16 h2f __attribute__((ext_vector_type(2)));

// f32 += dot(half2, half2) with f32 accumulation (v_dot2_f32_f16).
__device__ __forceinline__ float fdot2h(unsigned a, unsigned b, float c) {
#if __has_builtin(__builtin_amdgcn_fdot2)
    return __builtin_amdgcn_fdot2(__builtin_bit_cast(h2f, a),
                                  __builtin_bit_cast(h2f, b), c, false);
#else
    float2 af = __half22float2(__builtin_bit_cast(__half2, a));
    float2 bf = __half22float2(__builtin_bit_cast(__half2, b));
    return c + af.x * bf.x + af.y * bf.y;
#endif
}

__device__ __forceinline__ unsigned pack2(float a, float b) {
    return __builtin_bit_cast(unsigned, __floats2half2_rn(a, b));
}

__global__ __launch_bounds__(256) void init_out_kernel(const float* __restrict__ bias,
                                                       float* __restrict__ out) {
    int i = blockIdx.x * 256 + threadIdx.x;
    out[i] = bias[i & 63];
}

// ---------------- Phase 1: Xh = half2(Xr, Xi), [N][64]; zero hist counts ----------------
__global__ __launch_bounds__(256) void xh_zero_kernel(const float* __restrict__ Xr,
                                                      const float* __restrict__ Xi,
                                                      unsigned* __restrict__ Xh,
                                                      int* __restrict__ counts) {
    int i = blockIdx.x * 256 + threadIdx.x;   // grid = N*64/4/256 = 6250 exact
    if (i < NP) counts[i] = 0;
    const float4 r = ((const float4*)Xr)[i];
    const float4 m = ((const float4*)Xi)[i];
    uint4 u;
    u.x = pack2(r.x, m.x);
    u.y = pack2(r.y, m.y);
    u.z = pack2(r.z, m.z);
    u.w = pack2(r.w, m.w);
    ((uint4*)Xh)[i] = u;
}

// ---------------- CSR build ----------------
__global__ __launch_bounds__(256) void hist_kernel(const int* __restrict__ rows,
                                                   int* __restrict__ counts) {
    int e = blockIdx.x * 256 + threadIdx.x;
    if (e < E_EDGES) atomicAdd(&counts[rows[e]], 1);
}

__global__ __launch_bounds__(256) void scan_a_kernel(const int* __restrict__ counts,
                                                     int* __restrict__ rowst,
                                                     int* __restrict__ btot) {
    __shared__ int s[256];
    const int t = threadIdx.x;
    const int g = blockIdx.x * 256 + t;
    int v = counts[g];
    s[t] = v;
    __syncthreads();
    for (int off = 1; off < 256; off <<= 1) {
        int a = (t >= off) ? s[t - off] : 0;
        __syncthreads();
        s[t] += a;
        __syncthreads();
    }
    rowst[g] = s[t] - v;
    if (t == 255) btot[blockIdx.x] = s[255];
}

__global__ __launch_bounds__(512) void scan_b_kernel(int* __restrict__ btot) {
    __shared__ int s[512];
    const int t = threadIdx.x;
    int v = (t < NBLK) ? btot[t] : 0;
    s[t] = v;
    __syncthreads();
    for (int off = 1; off < 512; off <<= 1) {
        int a = (t >= off) ? s[t - off] : 0;
        __syncthreads();
        s[t] += a;
        __syncthreads();
    }
    if (t < NBLK) btot[t] = s[t] - v;
}

__global__ __launch_bounds__(256) void scan_c_kernel(const int* __restrict__ btot,
                                                     int* __restrict__ rowst,
                                                     int* __restrict__ cursor) {
    const int g = blockIdx.x * 256 + threadIdx.x;
    int v = rowst[g] + btot[blockIdx.x];
    rowst[g] = v;
    cursor[g] = v;
}

// payload per edge (32 B): {col, (lr0,-li0), (li0,lr0), (lr1,-li1)} {(li1,lr1), (lr2,-li2), (li2,lr2), 0}
__global__ __launch_bounds__(256) void scatter_kernel(const int* __restrict__ rows,
                                                      const int* __restrict__ cols,
                                                      const float* __restrict__ Lr,
                                                      const float* __restrict__ Li,
                                                      int* __restrict__ cursor,
                                                      uint4* __restrict__ payload) {
    int e = blockIdx.x * 256 + threadIdx.x;
    if (e >= E_EDGES) return;
    int r = rows[e];
    int pos = atomicAdd(&cursor[r], 1);
    const float lr0 = Lr[e], li0 = Li[e];
    const float lr1 = Lr[E_EDGES + e], li1 = Li[E_EDGES + e];
    const float lr2 = Lr[2 * E_EDGES + e], li2 = Li[2 * E_EDGES + e];
    uint4 u0, u1;
    u0.x = (unsigned)cols[e];
    u0.y = pack2(lr0, -li0);
    u0.z = pack2(li0, lr0);
    u0.w = pack2(lr1, -li1);
    u1.x = pack2(li1, lr1);
    u1.y = pack2(lr2, -li2);
    u1.z = pack2(li2, lr2);
    u1.w = 0u;
    payload[2 * (size_t)pos] = u0;
    payload[2 * (size_t)pos + 1] = u1;
}

// ---------------- Main pass: one wave per row, scalar payload + dot2 ----------------
__global__ __launch_bounds__(256) void row3_kernel(const int* __restrict__ rowst,
                                                   const uint4* __restrict__ payload,
                                                   const unsigned* __restrict__ Xh,
                                                   __half* __restrict__ Yre,
                                                   __half* __restrict__ Yim) {
    // Wave-uniform row index: lets the compiler prove payload addresses uniform
    // and emit s_load (scalar pipe) for the payload stream.
    const int r = __builtin_amdgcn_readfirstlane(blockIdx.x * 4 + ((int)threadIdx.x >> 6));
    const int lane = threadIdx.x & 63;
    if (r >= N_NODES) return;
    const int start = rowst[r];
    const int end = rowst[r + 1];
    const int n = end - start;

    float aR0 = 0.f, aI0 = 0.f, aR1 = 0.f, aI1 = 0.f, aR2 = 0.f, aI2 = 0.f;

    auto gx = [&](unsigned col) -> unsigned { return Xh[(size_t)col * 64 + lane]; };
    auto accum = [&](const uint4& q0, const uint4& q1, unsigned xv) {
        aR0 = fdot2h(q0.y, xv, aR0);
        aI0 = fdot2h(q0.z, xv, aI0);
        aR1 = fdot2h(q0.w, xv, aR1);
        aI1 = fdot2h(q1.x, xv, aI1);
        aR2 = fdot2h(q1.y, xv, aR2);
        aI2 = fdot2h(q1.z, xv, aI2);
    };

    if (n > 0) {
        int p = start;
        uint4 a0 = payload[2 * (size_t)p], a1 = payload[2 * (size_t)p + 1];
        unsigned xA = gx(a0.x);
        uint4 b0, b1, c0, c1;
        b0.x = b0.y = b0.z = b0.w = 0u;
        b1 = b0; c0 = b0; c1 = b0;
        unsigned xB = 0u;
        if (n > 1) {
            b0 = payload[2 * (size_t)(p + 1)];
            b1 = payload[2 * (size_t)(p + 1) + 1];
            xB = gx(b0.x);
        }
        if (n > 2) {
            c0 = payload[2 * (size_t)(p + 2)];
            c1 = payload[2 * (size_t)(p + 2) + 1];
        }
        for (; p + 3 < end; ++p) {
            unsigned xC = gx(c0.x);                       // gather for p+2: 2 iters of slack
            uint4 d0 = payload[2 * (size_t)(p + 3)];      // payload for p+3 (scalar pipe)
            uint4 d1 = payload[2 * (size_t)(p + 3) + 1];
            accum(a0, a1, xA);
            a0 = b0; a1 = b1; xA = xB;
            b0 = c0; b1 = c1; xB = xC;
            c0 = d0; c1 = d1;
        }
        // rem = end - p in {1,2,3}
        accum(a0, a1, xA);
        if (p + 1 < end) accum(b0, b1, xB);
        if (p + 2 < end) {
            unsigned xC = gx(c0.x);
            accum(c0, c1, xC);
        }
    }

    __half* yr = Yre + (size_t)r * 192;
    __half* yi = Yim + (size_t)r * 192;
    yr[lane] = __float2half(aR0);
    yr[64 + lane] = __float2half(aR1);
    yr[128 + lane] = __float2half(aR2);
    yi[lane] = __float2half(aI0);
    yi[64 + lane] = __float2half(aI1);
    yi[128 + lane] = __float2half(aI2);
}

// ---------------- Phase 4: out = Y @ Wcat + bias via packed-pair dot2 ----------------
// Yre/Yim: [N][192] f16 (t = k*64 + j). Wcat: [192][64] f32 (row-major [3][64][64]).
__global__ __launch_bounds__(256) void yw2_kernel(const __half* __restrict__ Yre,
                                                  const __half* __restrict__ Yim,
                                                  const float* __restrict__ W,
                                                  const float* __restrict__ bias,
                                                  float* __restrict__ out) {
    __shared__ unsigned sW2[96][64];     // [t-pair][col] = half2(W[2t][c], W[2t+1][c])  24 KB
    __shared__ unsigned sY[2][32][96];   // [re/im][row][t-pair]                          24 KB
    const int tid = threadIdx.x;

    for (int idx = tid; idx < 96 * 64; idx += 256) {
        const int kp = idx >> 6, c = idx & 63;
        sW2[kp][c] = pack2(W[(2 * kp) * 64 + c], W[(2 * kp + 1) * 64 + c]);
    }

    const int rowbase = blockIdx.x * 32;                 // grid = N/32 = 3125 exact
    const uint4* gYr = (const uint4*)(Yre + (size_t)rowbase * 192);
    const uint4* gYi = (const uint4*)(Yim + (size_t)rowbase * 192);
    uint4* sYr4 = (uint4*)&sY[0][0][0];
    uint4* sYi4 = (uint4*)&sY[1][0][0];
    for (int i = tid; i < 768; i += 256) {
        sYr4[i] = gYr[i];
        sYi4[i] = gYi[i];
    }
    __syncthreads();

    const int col = tid & 63;
    const int rg = tid >> 6;
    const float b = bias[col];

    float accR[8], accI[8];
#pragma unroll
    for (int i = 0; i < 8; ++i) { accR[i] = 0.f; accI[i] = 0.f; }

#pragma unroll 4
    for (int kpp = 0; kpp < 48; ++kpp) {
        const unsigned w0 = sW2[2 * kpp][col];       // stride-1 across lanes: conflict-free
        const unsigned w1 = sW2[2 * kpp + 1][col];
#pragma unroll
        for (int i = 0; i < 8; ++i) {
            const int row = rg * 8 + i;
            u32x2 yr = *(const u32x2*)&sY[0][row][2 * kpp];   // uniform addr -> broadcast
            u32x2 yi = *(const u32x2*)&sY[1][row][2 * kpp];
            accR[i] = fdot2h(yr.x, w0, accR[i]);
            accR[i] = fdot2h(yr.y, w1, accR[i]);
            accI[i] = fdot2h(yi.x, w0, accI[i]);
            accI[i] = fdot2h(yi.y, w1, accI[i]);
        }
    }

#pragma unroll
    for (int i = 0; i < 8; ++i) {
        const int row = rowbase + rg * 8 + i;
        __builtin_nontemporal_store(accR[i] + b, &out[(size_t)row * 64 + col]);
        __builtin_nontemporal_store(accI[i] + b, &out[(size_t)(N_NODES + row) * 64 + col]);
    }
}

// ================= Fallback kernels (small-ws paths) =================
template <int NK>
__global__ __launch_bounds__(256) void xw_kernel(const float* __restrict__ Xr,
                                                 const float* __restrict__ Xi,
                                                 const float* __restrict__ W,
                                                 __half2* __restrict__ XWh) {
    __shared__ float sW[NK][64][64];
    __shared__ float4 sX4[2][32][16];
    const int tid = threadIdx.x;

    float4* swf = (float4*)&sW[0][0][0];
    const float4* gW = (const float4*)W;
    for (int i = tid; i < NK * 1024; i += 256) swf[i] = gW[i];

    const int rowbase = blockIdx.x * 32;
    float4* sxf = (float4*)sX4;
    const float4* gXr = (const float4*)(Xr + (size_t)rowbase * CH);
    const float4* gXi = (const float4*)(Xi + (size_t)rowbase * CH);
    for (int i = tid; i < 512; i += 256) {
        sxf[i] = gXr[i];
        sxf[512 + i] = gXi[i];
    }
    __syncthreads();

    const int col = tid & 63;
    const int rg = tid >> 6;

    float acc[8][2 * NK];
#pragma unroll
    for (int i = 0; i < 8; ++i)
#pragma unroll
        for (int c2 = 0; c2 < 2 * NK; ++c2) acc[i][c2] = 0.0f;

#pragma unroll 2
    for (int j4 = 0; j4 < 16; ++j4) {
        float w[NK][4];
#pragma unroll
        for (int k = 0; k < NK; ++k)
#pragma unroll
            for (int jj = 0; jj < 4; ++jj) w[k][jj] = sW[k][j4 * 4 + jj][col];
#pragma unroll
        for (int i = 0; i < 8; ++i) {
            float4 xr = sX4[0][rg * 8 + i][j4];
            float4 xi = sX4[1][rg * 8 + i][j4];
            const float xra[4] = {xr.x, xr.y, xr.z, xr.w};
            const float xia[4] = {xi.x, xi.y, xi.z, xi.w};
#pragma unroll
            for (int jj = 0; jj < 4; ++jj)
#pragma unroll
                for (int k = 0; k < NK; ++k) {
                    acc[i][2 * k] += xra[jj] * w[k][jj];
                    acc[i][2 * k + 1] += xia[jj] * w[k][jj];
                }
        }
    }

#pragma unroll
    for (int i = 0; i < 8; ++i) {
        __half2* dst = XWh + (size_t)(rowbase + rg * 8 + i) * (NK * 64);
#pragma unroll
        for (int k = 0; k < NK; ++k)
            dst[k * 64 + col] = __floats2half2_rn(acc[i][2 * k], acc[i][2 * k + 1]);
    }
}

template <int NK>
__global__ __launch_bounds__(256) void edge_kernel(const int* __restrict__ rows,
                                                   const int* __restrict__ cols,
                                                   const float* __restrict__ Lr,
                                                   const float* __restrict__ Li,
                                                   const __half2* __restrict__ XWh,
                                                   float* __restrict__ out) {
    const int gid = blockIdx.x * 256 + threadIdx.x;
    const int e = gid >> 6;
    const int lane = gid & 63;
    if (e >= E_EDGES) return;

    const int row = rows[e];
    const int colN = cols[e];
    const __half2* xw = XWh + (size_t)colN * (NK * 64);

    float rc = 0.0f, ic = 0.0f;
#pragma unroll
    for (int k = 0; k < NK; ++k) {
        const float lr = Lr[(size_t)k * E_EDGES + e];
        const float li = Li[(size_t)k * E_EDGES + e];
        float2 v = __half22float2(xw[k * 64 + lane]);
        rc += lr * v.x - li * v.y;
        ic += li * v.x + lr * v.y;
    }
    unsafeAtomicAdd(out + (size_t)row * 64 + lane, rc);
    unsafeAtomicAdd(out + ((size_t)N_NODES + row) * 64 + lane, ic);
}

extern "C" void kernel_launch(void* const* d_in, const int* in_sizes, int n_in,
                              void* d_out, int out_size, void* d_ws, size_t ws_size,
                              hipStream_t stream) {
    const float* Xr = (const float*)d_in[0];
    const float* Xi = (const float*)d_in[1];
    const int* ei = (const int*)d_in[2];
    const float* Lr = (const float*)d_in[3];
    const float* Li = (const float*)d_in[4];
    const float* W = (const float*)d_in[5];
    const float* bias = (const float*)d_in[6];
    float* out = (float*)d_out;

    const int* rows = ei;
    const int* cols = ei + E_EDGES;

    char* wsb = (char*)d_ws;
    const int e_grid = E_EDGES / 256;                             // 6250
    const int edge_grid = (int)((size_t)E_EDGES * 64 / 256);      // 400000
    const int gemm_grid = N_NODES / 32;                           // 3125

    // Main-path ws layout
    unsigned* Xh = (unsigned*)wsb;                                //  25,600,000 B
    __half* Yre = (__half*)(wsb + 25600000);                      //  38,400,000 B
    __half* Yim = (__half*)(wsb + 64000000);                      //  38,400,000 B
    uint4* payload = (uint4*)(wsb + 102400000);                   //  51,200,000 B (32 B/edge)
    int* counts = (int*)(wsb + 153600000);                        //     400,384 B
    int* rowst = (int*)(wsb + 154000384);                         //     400,384 B
    int* cursor = (int*)(wsb + 154400768);                        //     400,384 B
    int* btot = (int*)(wsb + 154801152);                          //       2,048 B
    const size_t need_new = 154803200;

    if (ws_size >= need_new) {
        xh_zero_kernel<<<6250, 256, 0, stream>>>(Xr, Xi, Xh, counts);
        hist_kernel<<<e_grid, 256, 0, stream>>>(rows, counts);
        scan_a_kernel<<<NBLK, 256, 0, stream>>>(counts, rowst, btot);
        scan_b_kernel<<<1, 512, 0, stream>>>(btot);
        scan_c_kernel<<<NBLK, 256, 0, stream>>>(btot, rowst, cursor);
        scatter_kernel<<<e_grid, 256, 0, stream>>>(rows, cols, Lr, Li, cursor, payload);
        row3_kernel<<<(N_NODES + 3) / 4, 256, 0, stream>>>(rowst, payload, Xh, Yre, Yim);
        yw2_kernel<<<gemm_grid, 256, 0, stream>>>(Yre, Yim, W, bias, out);
        return;
    }

    // Fallback ws layout (atomic edge scatter over XWh table)
    __half2* XWh = (__half2*)wsb;                                 //  76,800,000 B
    const size_t need_onepass = 76800000;

    if (ws_size >= need_onepass) {
        init_out_kernel<<<2 * N_NODES * CH / 256, 256, 0, stream>>>(bias, out);
        xw_kernel<3><<<gemm_grid, 256, 0, stream>>>(Xr, Xi, W, XWh);
        edge_kernel<3><<<edge_grid, 256, 0, stream>>>(rows, cols, Lr, Li, XWh, out);
    } else {
        init_out_kernel<<<2 * N_NODES * CH / 256, 256, 0, stream>>>(bias, out);
        for (int k = 0; k < 3; ++k) {
            xw_kernel<1><<<gemm_grid, 256, 0, stream>>>(Xr, Xi, W + (size_t)k * 4096, XWh);
            edge_kernel<1><<<edge_grid, 256, 0, stream>>>(rows, cols,
                                                          Lr + (size_t)k * E_EDGES,
                                                          Li + (size_t)k * E_EDGES, XWh, out);
        }
    }
}